// Round 6
// baseline (579.580 us; speedup 1.0000x reference)
//
#include <hip/hip_runtime.h>
#include <stdint.h>

typedef unsigned short u16;
typedef __bf16 bf16x8 __attribute__((ext_vector_type(8)));
typedef float f32x4 __attribute__((ext_vector_type(4)));

#define DEV static __device__ __forceinline__

DEV u16 f2b(float f) {                       // f32 -> bf16 RNE
    unsigned u = __float_as_uint(f);
    u += 0x7FFF + ((u >> 16) & 1);
    return (u16)(u >> 16);
}
DEV float b2f(u16 h) { return __uint_as_float((unsigned)h << 16); }

DEV void load16(const void* g, void* l) {    // async global->LDS, 16B/lane
    __builtin_amdgcn_global_load_lds((const __attribute__((address_space(1))) void*)g,
                                     (__attribute__((address_space(3))) void*)l, 16, 0, 0);
}

// ---------------- all weights f32 -> bf16, one dispatch ----------------
// dst layout (contiguous): Wk,Wv,Wr | Wo | Fk | Fv | Fr
__global__ __launch_bounds__(256) void cvt_all(
    const float* __restrict__ Wk, const float* __restrict__ Wv,
    const float* __restrict__ Wr, const float* __restrict__ Wo,
    const float* __restrict__ Fk, const float* __restrict__ Fv,
    const float* __restrict__ Fr, u16* __restrict__ dst) {
    const int CC = 512 * 512, HC = 2048 * 512;
    int e = (blockIdx.x * 256 + threadIdx.x) * 4;
    const float* s; int base;
    if      (e < 1 * CC)      { s = Wk; base = 0; }
    else if (e < 2 * CC)      { s = Wv; base = 1 * CC; }
    else if (e < 3 * CC)      { s = Wr; base = 2 * CC; }
    else if (e < 4 * CC)      { s = Wo; base = 3 * CC; }
    else if (e < 4 * CC + HC) { s = Fk; base = 4 * CC; }
    else if (e < 4 * CC + 2 * HC) { s = Fv; base = 4 * CC + HC; }
    else                      { s = Fr; base = 4 * CC + 2 * HC; }
    float4 f = *(const float4*)(s + (e - base));
    ushort4 o;
    o.x = f2b(f.x); o.y = f2b(f.y); o.z = f2b(f.z); o.w = f2b(f.w);
    *(ushort4*)(dst + e) = o;
}

// ---------------- sequential LayerNorm + time-shift mix ----------------
// One block per batch element b; iterates t, caching LN(row t-1) in regs.
template <int NOUT>
__global__ __launch_bounds__(256) void ln_seq(
    const float* __restrict__ x, const float* __restrict__ g, const float* __restrict__ be,
    const float* __restrict__ mk, const float* __restrict__ mv, const float* __restrict__ mr,
    u16* __restrict__ ok, u16* __restrict__ ov, u16* __restrict__ orr, int T) {
    const int C = 512;
    int b = blockIdx.x;
    int tid = threadIdx.x;
    int c = tid * 2;
    const float* xb = x + (size_t)b * T * C;
    float g0 = g[c], g1 = g[c + 1], be0 = be[c], be1 = be[c + 1];
    float k0 = mk[c], k1 = mk[c + 1];
    float v0 = 0.f, v1 = 0.f;
    if (NOUT == 3) { v0 = mv[c]; v1 = mv[c + 1]; }
    float r0 = mr[c], r1 = mr[c + 1];
    __shared__ float sm[2][8];
    float h0p = 0.f, h1p = 0.f;
    size_t idx = (size_t)b * T * C + c;
    for (int t = 0; t < T; ++t) {
        float2 vt = *(const float2*)(xb + (size_t)t * C + c);
        float s0 = vt.x + vt.y, s1 = vt.x * vt.x + vt.y * vt.y;
#pragma unroll
        for (int off = 32; off; off >>= 1) {
            s0 += __shfl_down(s0, off); s1 += __shfl_down(s1, off);
        }
        int w = tid >> 6;
        if ((tid & 63) == 0) { sm[t & 1][w * 2] = s0; sm[t & 1][w * 2 + 1] = s1; }
        __syncthreads();
        s0 = sm[t & 1][0] + sm[t & 1][2] + sm[t & 1][4] + sm[t & 1][6];
        s1 = sm[t & 1][1] + sm[t & 1][3] + sm[t & 1][5] + sm[t & 1][7];
        float mu = s0 * (1.f / 512.f);
        float var = s1 * (1.f / 512.f) - mu * mu;
        float rs = rsqrtf(var + 1e-5f);
        float h0 = (vt.x - mu) * rs * g0 + be0;
        float h1 = (vt.y - mu) * rs * g1 + be1;
        *(ushort2*)&ok[idx] = make_ushort2(f2b(h0 * k0 + h0p * (1.f - k0)),
                                           f2b(h1 * k1 + h1p * (1.f - k1)));
        if (NOUT == 3)
            *(ushort2*)&ov[idx] = make_ushort2(f2b(h0 * v0 + h0p * (1.f - v0)),
                                               f2b(h1 * v1 + h1p * (1.f - v1)));
        *(ushort2*)&orr[idx] = make_ushort2(f2b(h0 * r0 + h0p * (1.f - r0)),
                                            f2b(h1 * r1 + h1p * (1.f - r1)));
        h0p = h0; h1p = h1;
        idx += C;
    }
}

// ---------------- NT GEMM: out[n,d] = sum_c A[n,c]*B[d,c] ----------------
// BM=BN=128, BK=64; 4 waves 2x2, each 64x64 (acc 4x4). Double-buffered LDS,
// 2-phase pipeline: stage(next) issued before compute(cur), 1 barrier/K-step.
// LDS XOR-swizzle via pre-swizzled global source granule. Bijective XCD swizzle.
// EPI: 0 bf16 raw | 2 f32 v+Add | 3 bf16 relu^2 | 4 f32 Add+sig(v)*Mul
//      5 kvr mode: z<2 bf16 raw, z==2 bf16 sigmoid
template <int EPI>
__global__ __launch_bounds__(256) void gemm128(
    const u16* __restrict__ A0, int strideAz,
    const u16* __restrict__ B0, int strideBz,
    void* O0, void* O1, void* O2,
    const float* __restrict__ Add, const u16* __restrict__ Mul,
    int K, int D) {
    const int BM = 128, BN = 128, BK = 64;
    __shared__ __align__(16) u16 As[2][BM * BK];
    __shared__ __align__(16) u16 Bs[2][BN * BK];

    // bijective XCD-chunked swizzle (m204)
    int gx = gridDim.x, gy = gridDim.y;
    int fid = blockIdx.x + gx * (blockIdx.y + gy * blockIdx.z);
    int nwg = gx * gy * gridDim.z;
    int q = nwg >> 3, r = nwg & 7, xcd = fid & 7, jj = fid >> 3;
    int swz = (xcd < r ? xcd * (q + 1) : r * (q + 1) + (xcd - r) * q) + jj;
    int bx = swz % gx;
    int tmp = swz / gx;
    int by = tmp % gy;
    int bz = tmp / gy;

    const u16* A = A0 + (size_t)bz * strideAz;
    const u16* B = B0 + (size_t)bz * strideBz;
    void* Out = (bz == 0) ? O0 : (bz == 1) ? O1 : O2;

    int tid = threadIdx.x, lane = tid & 63, w = tid >> 6;
    int wm = w >> 1, wn = w & 1;
    int rowBase = by * BM, colBase = bx * BN;
    int l8 = lane >> 3;                       // row within 8-row staging chunk
    int gsrc = ((lane & 7) ^ l8) * 8;         // pre-swizzled source granule

    const int nt = K / BK;
    f32x4 acc[4][4] = {};

    auto stage = [&](int buf, int kt) {
#pragma unroll
        for (int i = 0; i < 4; ++i) {         // 8 rows per instr, 4 per wave
            int rr0 = w * 32 + i * 8;
            load16(A + (size_t)(rowBase + rr0 + l8) * K + kt + gsrc, &As[buf][rr0 * BK]);
            load16(B + (size_t)(colBase + rr0 + l8) * K + kt + gsrc, &Bs[buf][rr0 * BK]);
        }
    };

    stage(0, 0);
    __syncthreads();                          // drains vmcnt: buf0 ready
    int cur = 0;
    for (int t = 0; t < nt; ++t) {
        if (t + 1 < nt) stage(cur ^ 1, (t + 1) * BK);   // prefetch next tile
#pragma unroll
        for (int s = 0; s < 2; ++s) {
            bf16x8 af[4], bfv[4];
#pragma unroll
            for (int m = 0; m < 4; ++m) {
                int row = wm * 64 + m * 16 + (lane & 15);
                int gsw = (s * 4 + (lane >> 4)) ^ (row & 7);
                af[m] = *(const bf16x8*)&As[cur][row * BK + gsw * 8];
            }
#pragma unroll
            for (int n = 0; n < 4; ++n) {
                int col = wn * 64 + n * 16 + (lane & 15);
                int gsw = (s * 4 + (lane >> 4)) ^ (col & 7);
                bfv[n] = *(const bf16x8*)&Bs[cur][col * BK + gsw * 8];
            }
#pragma unroll
            for (int m = 0; m < 4; ++m)
#pragma unroll
                for (int n = 0; n < 4; ++n)
                    acc[m][n] = __builtin_amdgcn_mfma_f32_16x16x32_bf16(af[m], bfv[n], acc[m][n], 0, 0, 0);
        }
        __syncthreads();                      // drains vmcnt: next buf ready, cur free
        cur ^= 1;
    }

    int r0e = (lane >> 4) * 4;
    int ce = lane & 15;
#pragma unroll
    for (int m = 0; m < 4; ++m) {
#pragma unroll
        for (int n = 0; n < 4; ++n) {
            int row = rowBase + wm * 64 + m * 16 + r0e;
            int col = colBase + wn * 64 + n * 16 + ce;
#pragma unroll
            for (int rr = 0; rr < 4; ++rr) {
                size_t idx = (size_t)(row + rr) * D + col;
                float v = acc[m][n][rr];
                if (EPI == 0) {
                    ((u16*)Out)[idx] = f2b(v);
                } else if (EPI == 2) {
                    ((float*)Out)[idx] = v + Add[idx];
                } else if (EPI == 3) {
                    float rl = fmaxf(v, 0.f);
                    ((u16*)Out)[idx] = f2b(rl * rl);
                } else if (EPI == 4) {
                    float s = 1.f / (1.f + __expf(-v));
                    ((float*)Out)[idx] = Add[idx] + s * b2f(Mul[idx]);
                } else {                      // EPI 5: kvr
                    ((u16*)Out)[idx] = (bz == 2) ? f2b(1.f / (1.f + __expf(-v))) : f2b(v);
                }
            }
        }
    }
}

// ---------------- WKV recurrence (bf16 in/out) ----------------
__global__ __launch_bounds__(256) void wkv_kernel(
    const u16* __restrict__ k, const u16* __restrict__ v, const u16* __restrict__ sr,
    const float* __restrict__ td, const float* __restrict__ tf,
    u16* __restrict__ rwkv, int T) {
    const int C = 512;
    int gid = blockIdx.x * 256 + threadIdx.x;
    int c = gid & (C - 1);
    int b = gid >> 9;
    float w = -__expf(td[c]);
    float u = tf[c];
    float aa = 0.f, bb = 0.f, pp = -1e38f;
    size_t idx = (size_t)b * T * C + c;
    for (int t = 0; t < T; ++t, idx += C) {
        float kt = b2f(k[idx]), vt = b2f(v[idx]);
        float ww = u + kt;
        float p = fmaxf(pp, ww);
        float e1 = __expf(pp - p), e2 = __expf(ww - p);
        float y = (e1 * aa + e2 * vt) / (e1 * bb + e2);
        float ww2 = pp + w;
        float p2 = fmaxf(ww2, kt);
        float e1b = __expf(ww2 - p2), e2b = __expf(kt - p2);
        aa = e1b * aa + e2b * vt;
        bb = e1b * bb + e2b;
        pp = p2;
        rwkv[idx] = f2b(b2f(sr[idx]) * y);
    }
}

extern "C" void kernel_launch(void* const* d_in, const int* in_sizes, int n_in,
                              void* d_out, int out_size, void* d_ws, size_t ws_size,
                              hipStream_t stream) {
    const int B = 512, T = 50, C = 512, H = 2048;
    const int NT = B * T;   // 25600

    const float* x     = (const float*)d_in[0];
    const float* ln1_g = (const float*)d_in[1];
    const float* ln1_b = (const float*)d_in[2];
    const float* ln2_g = (const float*)d_in[3];
    const float* ln2_b = (const float*)d_in[4];
    const float* amk   = (const float*)d_in[5];
    const float* amv   = (const float*)d_in[6];
    const float* amr   = (const float*)d_in[7];
    const float* td    = (const float*)d_in[8];
    const float* tf    = (const float*)d_in[9];
    const float* Wk    = (const float*)d_in[10];
    const float* Wv    = (const float*)d_in[11];
    const float* Wr    = (const float*)d_in[12];
    const float* Wo    = (const float*)d_in[13];
    const float* fmk   = (const float*)d_in[14];
    const float* fmr   = (const float*)d_in[15];
    const float* Fk    = (const float*)d_in[16];
    const float* Fv    = (const float*)d_in[17];
    const float* Fr    = (const float*)d_in[18];
    float* out = (float*)d_out;

    // ---- chunk rows R (must divide 25600; multiple of lcm(50,256)=6400) ----
    const size_t WBYTES = ((size_t)C*C*2)*6 + ((size_t)H*C*2)*2 + 4096;
    int R = 6400;
    if (ws_size >= (size_t)25600 * 1024 * 7 + WBYTES)      R = 25600;
    else if (ws_size >= (size_t)12800 * 1024 * 7 + WBYTES) R = 12800;
    const int NCH = NT / R;

    char* ws = (char*)d_ws;
    size_t off = 0;
    auto alloc = [&](size_t bytes) {
        char* p = ws + off;
        off += (bytes + 255) & ~(size_t)255;
        return p;
    };
    const size_t uc = (size_t)R * C * 2;    // one bf16 unit [R][C]
    u16*   U0 = (u16*)alloc(uc);            // xk -> rwkv -> kk(2 units w/ U1)
    u16*   U1 = (u16*)alloc(uc);            // xv
    u16*   U2 = (u16*)alloc(uc);            // xr -> kv
    u16*   U3 = (u16*)alloc(uc);            // k  -> fk
    u16*   U4 = (u16*)alloc(uc);            // v  -> fr
    float* X2 = (float*)alloc((size_t)R * C * 4);   // first half doubles as sr (U5)
    u16*   U5 = (u16*)X2;                   // sr (dead before X2 written)
    // weight block: contiguous (all sizes multiples of 256B)
    u16* bWkvr = (u16*)alloc((size_t)3 * C * C * 2);
    u16* bWo   = (u16*)alloc((size_t)C * C * 2);
    u16* bFk   = (u16*)alloc((size_t)H * C * 2);
    u16* bFv   = (u16*)alloc((size_t)C * H * 2);
    u16* bFr   = (u16*)alloc((size_t)C * C * 2);
    u16* kk = U0;   // [R/2][H] bf16 == exactly U0+U1 (contiguous)

    // all weights -> bf16, one dispatch (3328 blocks * 1024 elems)
    cvt_all<<<(5 * C * C + 2 * H * C) / 1024, 256, 0, stream>>>(
        Wk, Wv, Wr, Wo, Fk, Fv, Fr, bWkvr);

    for (int ch = 0; ch < NCH; ++ch) {
        const float* xc  = x   + (size_t)ch * R * C;
        float*       oc  = out + (size_t)ch * R * C;

        // ---- attention branch ----
        ln_seq<3><<<R / T, 256, 0, stream>>>(xc, ln1_g, ln1_b, amk, amv, amr, U0, U1, U2, T);
        gemm128<5><<<dim3(C / 128, R / 128, 3), 256, 0, stream>>>(
            U0, R * C, bWkvr, C * C, U3, U4, U5, nullptr, nullptr, C, C);
        wkv_kernel<<<(R / T) * C / 256, 256, 0, stream>>>(U3, U4, U5, td, tf, U0, T);
        gemm128<2><<<dim3(C / 128, R / 128, 1), 256, 0, stream>>>(
            U0, 0, bWo, 0, X2, nullptr, nullptr, xc, nullptr, C, C);

        // ---- FFN branch ----
        ln_seq<2><<<R / T, 256, 0, stream>>>(X2, ln2_g, ln2_b, fmk, nullptr, fmr, U3, nullptr, U4, T);
        for (int hh = 0; hh < 2; ++hh) {
            size_t ro = (size_t)hh * (R / 2);
            gemm128<3><<<dim3(H / 128, R / 256, 1), 256, 0, stream>>>(
                U3 + ro * C, 0, bFk, 0, kk, nullptr, nullptr, nullptr, nullptr, C, H);
            gemm128<0><<<dim3(C / 128, R / 256, 1), 256, 0, stream>>>(
                kk, 0, bFv, 0, U2 + ro * C, nullptr, nullptr, nullptr, nullptr, H, C);
        }
        gemm128<4><<<dim3(C / 128, R / 128, 1), 256, 0, stream>>>(
            U4, 0, bFr, 0, oc, nullptr, nullptr, X2, U2, C, C);
    }
}

// Round 7
// 571.861 us; speedup vs baseline: 1.0135x; 1.0135x over previous
//
#include <hip/hip_runtime.h>
#include <stdint.h>

typedef unsigned short u16;
typedef __bf16 bf16x8 __attribute__((ext_vector_type(8)));
typedef float f32x4 __attribute__((ext_vector_type(4)));

#define DEV static __device__ __forceinline__

DEV u16 f2b(float f) {                       // f32 -> bf16 RNE
    unsigned u = __float_as_uint(f);
    u += 0x7FFF + ((u >> 16) & 1);
    return (u16)(u >> 16);
}
DEV float b2f(u16 h) { return __uint_as_float((unsigned)h << 16); }

DEV void load16(const void* g, void* l) {    // async global->LDS, 16B/lane
    __builtin_amdgcn_global_load_lds((const __attribute__((address_space(1))) void*)g,
                                     (__attribute__((address_space(3))) void*)l, 16, 0, 0);
}

// ---------------- all weights f32 -> bf16, one dispatch ----------------
// dst layout (contiguous): Wk,Wv,Wr | Wo | Fk | Fv | Fr
__global__ __launch_bounds__(256) void cvt_all(
    const float* __restrict__ Wk, const float* __restrict__ Wv,
    const float* __restrict__ Wr, const float* __restrict__ Wo,
    const float* __restrict__ Fk, const float* __restrict__ Fv,
    const float* __restrict__ Fr, u16* __restrict__ dst) {
    const int CC = 512 * 512, HC = 2048 * 512;
    int e = (blockIdx.x * 256 + threadIdx.x) * 4;
    const float* s; int base;
    if      (e < 1 * CC)      { s = Wk; base = 0; }
    else if (e < 2 * CC)      { s = Wv; base = 1 * CC; }
    else if (e < 3 * CC)      { s = Wr; base = 2 * CC; }
    else if (e < 4 * CC)      { s = Wo; base = 3 * CC; }
    else if (e < 4 * CC + HC) { s = Fk; base = 4 * CC; }
    else if (e < 4 * CC + 2 * HC) { s = Fv; base = 4 * CC + HC; }
    else                      { s = Fr; base = 4 * CC + 2 * HC; }
    float4 f = *(const float4*)(s + (e - base));
    ushort4 o;
    o.x = f2b(f.x); o.y = f2b(f.y); o.z = f2b(f.z); o.w = f2b(f.w);
    *(ushort4*)(dst + e) = o;
}

// ---------------- chunked LayerNorm + time-shift mix ----------------
// Block = (batch b, t-chunk of 10). Recomputes LN of row t0-1 as halo, then
// iterates 10 rows caching LN(t-1) in regs. 5x parallelism vs per-batch.
template <int NOUT>
__global__ __launch_bounds__(256) void ln_chunk(
    const float* __restrict__ x, const float* __restrict__ g, const float* __restrict__ be,
    const float* __restrict__ mk, const float* __restrict__ mv, const float* __restrict__ mr,
    u16* __restrict__ ok, u16* __restrict__ ov, u16* __restrict__ orr, int T) {
    const int C = 512, TC = 10;
    int nch = T / TC;                        // 5
    int b = blockIdx.x / nch;
    int t0 = (blockIdx.x % nch) * TC;
    int tid = threadIdx.x;
    int c = tid * 2;
    const float* xb = x + (size_t)b * T * C;
    float g0 = g[c], g1 = g[c + 1], be0 = be[c], be1 = be[c + 1];
    float k0 = mk[c], k1 = mk[c + 1];
    float v0 = 0.f, v1 = 0.f;
    if (NOUT == 3) { v0 = mv[c]; v1 = mv[c + 1]; }
    float r0 = mr[c], r1 = mr[c + 1];
    __shared__ float sm[2][8];
    float h0p = 0.f, h1p = 0.f;
    int tstart = (t0 == 0) ? 0 : t0 - 1;
    for (int t = tstart; t < t0 + TC; ++t) {
        float2 vt = *(const float2*)(xb + (size_t)t * C + c);
        float s0 = vt.x + vt.y, s1 = vt.x * vt.x + vt.y * vt.y;
#pragma unroll
        for (int off = 32; off; off >>= 1) {
            s0 += __shfl_down(s0, off); s1 += __shfl_down(s1, off);
        }
        int w = tid >> 6;
        if ((tid & 63) == 0) { sm[t & 1][w * 2] = s0; sm[t & 1][w * 2 + 1] = s1; }
        __syncthreads();
        s0 = sm[t & 1][0] + sm[t & 1][2] + sm[t & 1][4] + sm[t & 1][6];
        s1 = sm[t & 1][1] + sm[t & 1][3] + sm[t & 1][5] + sm[t & 1][7];
        float mu = s0 * (1.f / 512.f);
        float var = s1 * (1.f / 512.f) - mu * mu;
        float rs = rsqrtf(var + 1e-5f);
        float h0 = (vt.x - mu) * rs * g0 + be0;
        float h1 = (vt.y - mu) * rs * g1 + be1;
        if (t >= t0) {
            size_t idx = (size_t)b * T * C + (size_t)t * C + c;
            *(ushort2*)&ok[idx] = make_ushort2(f2b(h0 * k0 + h0p * (1.f - k0)),
                                               f2b(h1 * k1 + h1p * (1.f - k1)));
            if (NOUT == 3)
                *(ushort2*)&ov[idx] = make_ushort2(f2b(h0 * v0 + h0p * (1.f - v0)),
                                                   f2b(h1 * v1 + h1p * (1.f - v1)));
            *(ushort2*)&orr[idx] = make_ushort2(f2b(h0 * r0 + h0p * (1.f - r0)),
                                                f2b(h1 * r1 + h1p * (1.f - r1)));
        }
        h0p = h0; h1p = h1;
    }
}

// ---------------- NT GEMM: out[n,d] = sum_c A[n,c]*B[d,c] ----------------
// m97 structure: BM=BN=128, BK=64, SINGLE-buffered 32 KiB LDS, 4 waves 2x2
// (each 64x64, acc 4x4), stage -> barrier -> compute -> barrier.
// LDS XOR-swizzle via pre-swizzled global source. Bijective XCD swizzle.
// EPI: 0 bf16 raw | 2 f32 v+Add | 3 bf16 relu^2 | 4 f32 Add+sig(v)*Mul
//      5 kvr mode: z<2 bf16 raw, z==2 bf16 sigmoid
template <int EPI>
__global__ __launch_bounds__(256) void gemm128(
    const u16* __restrict__ A0, int strideAz,
    const u16* __restrict__ B0, int strideBz,
    void* O0, void* O1, void* O2,
    const float* __restrict__ Add, const u16* __restrict__ Mul,
    int K, int D) {
    const int BM = 128, BN = 128, BK = 64;
    __shared__ __align__(16) u16 As[BM * BK];
    __shared__ __align__(16) u16 Bs[BN * BK];

    // bijective XCD-chunked swizzle (m204)
    int gx = gridDim.x, gy = gridDim.y;
    int fid = blockIdx.x + gx * (blockIdx.y + gy * blockIdx.z);
    int nwg = gx * gy * gridDim.z;
    int q = nwg >> 3, r = nwg & 7, xcd = fid & 7, jj = fid >> 3;
    int swz = (xcd < r ? xcd * (q + 1) : r * (q + 1) + (xcd - r) * q) + jj;
    int bx = swz % gx;
    int tmp = swz / gx;
    int by = tmp % gy;
    int bz = tmp / gy;

    const u16* A = A0 + (size_t)bz * strideAz;
    const u16* B = B0 + (size_t)bz * strideBz;
    void* Out = (bz == 0) ? O0 : (bz == 1) ? O1 : O2;

    int tid = threadIdx.x, lane = tid & 63, w = tid >> 6;
    int wm = w >> 1, wn = w & 1;
    int rowBase = by * BM, colBase = bx * BN;
    int l8 = lane >> 3;                       // row within 8-row staging chunk
    int gsrc = ((lane & 7) ^ l8) * 8;         // pre-swizzled source granule

    const int nt = K / BK;
    f32x4 acc[4][4] = {};

    for (int t = 0; t < nt; ++t) {
        int kt = t * BK;
#pragma unroll
        for (int i = 0; i < 4; ++i) {         // 8 rows per instr, 4 per wave
            int rr0 = w * 32 + i * 8;
            load16(A + (size_t)(rowBase + rr0 + l8) * K + kt + gsrc, &As[rr0 * BK]);
            load16(B + (size_t)(colBase + rr0 + l8) * K + kt + gsrc, &Bs[rr0 * BK]);
        }
        __syncthreads();                      // drains vmcnt: tile ready
#pragma unroll
        for (int s = 0; s < 2; ++s) {
            bf16x8 af[4], bfv[4];
#pragma unroll
            for (int m = 0; m < 4; ++m) {
                int row = wm * 64 + m * 16 + (lane & 15);
                int gsw = (s * 4 + (lane >> 4)) ^ (row & 7);
                af[m] = *(const bf16x8*)&As[row * BK + gsw * 8];
            }
#pragma unroll
            for (int n = 0; n < 4; ++n) {
                int col = wn * 64 + n * 16 + (lane & 15);
                int gsw = (s * 4 + (lane >> 4)) ^ (col & 7);
                bfv[n] = *(const bf16x8*)&Bs[col * BK + gsw * 8];
            }
#pragma unroll
            for (int m = 0; m < 4; ++m)
#pragma unroll
                for (int n = 0; n < 4; ++n)
                    acc[m][n] = __builtin_amdgcn_mfma_f32_16x16x32_bf16(af[m], bfv[n], acc[m][n], 0, 0, 0);
        }
        __syncthreads();                      // tile consumed, LDS free
    }

    int r0e = (lane >> 4) * 4;
    int ce = lane & 15;
#pragma unroll
    for (int m = 0; m < 4; ++m) {
#pragma unroll
        for (int n = 0; n < 4; ++n) {
            int row = rowBase + wm * 64 + m * 16 + r0e;
            int col = colBase + wn * 64 + n * 16 + ce;
#pragma unroll
            for (int rr = 0; rr < 4; ++rr) {
                size_t idx = (size_t)(row + rr) * D + col;
                float v = acc[m][n][rr];
                if (EPI == 0) {
                    ((u16*)Out)[idx] = f2b(v);
                } else if (EPI == 2) {
                    ((float*)Out)[idx] = v + Add[idx];
                } else if (EPI == 3) {
                    float rl = fmaxf(v, 0.f);
                    ((u16*)Out)[idx] = f2b(rl * rl);
                } else if (EPI == 4) {
                    float s = 1.f / (1.f + __expf(-v));
                    ((float*)Out)[idx] = Add[idx] + s * b2f(Mul[idx]);
                } else {                      // EPI 5: kvr
                    ((u16*)Out)[idx] = (bz == 2) ? f2b(1.f / (1.f + __expf(-v))) : f2b(v);
                }
            }
        }
    }
}

// ---------------- WKV recurrence (bf16 in/out) ----------------
__global__ __launch_bounds__(256) void wkv_kernel(
    const u16* __restrict__ k, const u16* __restrict__ v, const u16* __restrict__ sr,
    const float* __restrict__ td, const float* __restrict__ tf,
    u16* __restrict__ rwkv, int T) {
    const int C = 512;
    int gid = blockIdx.x * 256 + threadIdx.x;
    int c = gid & (C - 1);
    int b = gid >> 9;
    float w = -__expf(td[c]);
    float u = tf[c];
    float aa = 0.f, bb = 0.f, pp = -1e38f;
    size_t idx = (size_t)b * T * C + c;
    for (int t = 0; t < T; ++t, idx += C) {
        float kt = b2f(k[idx]), vt = b2f(v[idx]);
        float ww = u + kt;
        float p = fmaxf(pp, ww);
        float e1 = __expf(pp - p), e2 = __expf(ww - p);
        float y = (e1 * aa + e2 * vt) / (e1 * bb + e2);
        float ww2 = pp + w;
        float p2 = fmaxf(ww2, kt);
        float e1b = __expf(ww2 - p2), e2b = __expf(kt - p2);
        aa = e1b * aa + e2b * vt;
        bb = e1b * bb + e2b;
        pp = p2;
        rwkv[idx] = f2b(b2f(sr[idx]) * y);
    }
}

extern "C" void kernel_launch(void* const* d_in, const int* in_sizes, int n_in,
                              void* d_out, int out_size, void* d_ws, size_t ws_size,
                              hipStream_t stream) {
    const int B = 512, T = 50, C = 512, H = 2048;
    const int NT = B * T;   // 25600

    const float* x     = (const float*)d_in[0];
    const float* ln1_g = (const float*)d_in[1];
    const float* ln1_b = (const float*)d_in[2];
    const float* ln2_g = (const float*)d_in[3];
    const float* ln2_b = (const float*)d_in[4];
    const float* amk   = (const float*)d_in[5];
    const float* amv   = (const float*)d_in[6];
    const float* amr   = (const float*)d_in[7];
    const float* td    = (const float*)d_in[8];
    const float* tf    = (const float*)d_in[9];
    const float* Wk    = (const float*)d_in[10];
    const float* Wv    = (const float*)d_in[11];
    const float* Wr    = (const float*)d_in[12];
    const float* Wo    = (const float*)d_in[13];
    const float* fmk   = (const float*)d_in[14];
    const float* fmr   = (const float*)d_in[15];
    const float* Fk    = (const float*)d_in[16];
    const float* Fv    = (const float*)d_in[17];
    const float* Fr    = (const float*)d_in[18];
    float* out = (float*)d_out;

    // ---- chunk rows R (must divide 25600; multiple of lcm(50,256)=6400) ----
    const size_t WBYTES = ((size_t)C*C*2)*6 + ((size_t)H*C*2)*2 + 4096;
    int R = 6400;
    if (ws_size >= (size_t)25600 * 1024 * 7 + WBYTES)      R = 25600;
    else if (ws_size >= (size_t)12800 * 1024 * 7 + WBYTES) R = 12800;
    const int NCH = NT / R;

    char* ws = (char*)d_ws;
    size_t off = 0;
    auto alloc = [&](size_t bytes) {
        char* p = ws + off;
        off += (bytes + 255) & ~(size_t)255;
        return p;
    };
    const size_t uc = (size_t)R * C * 2;    // one bf16 unit [R][C]
    u16*   U0 = (u16*)alloc(uc);            // xk -> rwkv -> kk(2 units w/ U1)
    u16*   U1 = (u16*)alloc(uc);            // xv
    u16*   U2 = (u16*)alloc(uc);            // xr -> kv
    u16*   U3 = (u16*)alloc(uc);            // k  -> fk
    u16*   U4 = (u16*)alloc(uc);            // v  -> fr
    float* X2 = (float*)alloc((size_t)R * C * 4);   // first half doubles as sr (U5)
    u16*   U5 = (u16*)X2;                   // sr (dead before X2 written)
    // weight block: contiguous (all sizes multiples of 256B)
    u16* bWkvr = (u16*)alloc((size_t)3 * C * C * 2);
    u16* bWo   = (u16*)alloc((size_t)C * C * 2);
    u16* bFk   = (u16*)alloc((size_t)H * C * 2);
    u16* bFv   = (u16*)alloc((size_t)C * H * 2);
    u16* bFr   = (u16*)alloc((size_t)C * C * 2);
    u16* kk = U0;   // [R/2][H] bf16 == exactly U0+U1 (contiguous)

    // all weights -> bf16, one dispatch
    cvt_all<<<(5 * C * C + 2 * H * C) / 1024, 256, 0, stream>>>(
        Wk, Wv, Wr, Wo, Fk, Fv, Fr, bWkvr);

    for (int ch = 0; ch < NCH; ++ch) {
        const float* xc  = x   + (size_t)ch * R * C;
        float*       oc  = out + (size_t)ch * R * C;

        // ---- attention branch ----
        ln_chunk<3><<<(R / T) * 5, 256, 0, stream>>>(xc, ln1_g, ln1_b, amk, amv, amr, U0, U1, U2, T);
        gemm128<5><<<dim3(C / 128, R / 128, 3), 256, 0, stream>>>(
            U0, R * C, bWkvr, C * C, U3, U4, U5, nullptr, nullptr, C, C);
        wkv_kernel<<<(R / T) * C / 256, 256, 0, stream>>>(U3, U4, U5, td, tf, U0, T);
        gemm128<2><<<dim3(C / 128, R / 128, 1), 256, 0, stream>>>(
            U0, 0, bWo, 0, X2, nullptr, nullptr, xc, nullptr, C, C);

        // ---- FFN branch ----
        ln_chunk<2><<<(R / T) * 5, 256, 0, stream>>>(X2, ln2_g, ln2_b, fmk, nullptr, fmr, U3, nullptr, U4, T);
        for (int hh = 0; hh < 2; ++hh) {
            size_t ro = (size_t)hh * (R / 2);
            gemm128<3><<<dim3(H / 128, R / 256, 1), 256, 0, stream>>>(
                U3 + ro * C, 0, bFk, 0, kk, nullptr, nullptr, nullptr, nullptr, C, H);
            gemm128<0><<<dim3(C / 128, R / 256, 1), 256, 0, stream>>>(
                kk, 0, bFv, 0, U2 + ro * C, nullptr, nullptr, nullptr, nullptr, H, C);
        }
        gemm128<4><<<dim3(C / 128, R / 128, 1), 256, 0, stream>>>(
            U4, 0, bFr, 0, oc, nullptr, nullptr, X2, U2, C, C);
    }
}